// Round 3
// baseline (56.343 us; speedup 1.0000x reference)
//
#include <hip/hip_runtime.h>
#include <math.h>

// Problem constants (fixed by the reference): B=2, N=64, CI=CO=32
#define NZ 2
#define NN 64
#define NCI 32
#define NCO 32
#define NBLOCKS 256

// ws float layout (all zeroed by the memset node each call):
//   QA  [2][3][32] : offset 0    (coeff of -g_a[x])
//   QB  [2][3][32] : offset 192  (coeff of +g_b[x])
//   gam [2][32]    : offset 384
//   ctr (uint)     : offset 448
#define WS_QA  0
#define WS_QB  192
#define WS_GAM 384
#define WS_CTR 448

__device__ __forceinline__ void ld4(const float* __restrict__ p, float* d) {
    const float4 v = *(const float4*)p;
    d[0] = v.x; d[1] = v.y; d[2] = v.z; d[3] = v.w;
}

// Single fused kernel. 256 blocks x 256 threads; all blocks co-resident
// (4 waves, 6 KB LDS per block on 256 CUs), so the atomic grid barrier
// cannot deadlock.
//
// Phase 1 (per block = one 32-pair slice of one z):
//   partial ft/Gs/Gd over its (c,d) pairs  ->  fold W (linear!)  ->
//   unsafeAtomicAdd 224-float table contribution into ws (agent scope).
// Barrier: device-scope counter, release add + acquire spin.
// Phase 2: read finished QA/QB/gam tables, write 32 (a,b) rows of output.
__global__ __launch_bounds__(256) void k_fused(const float* __restrict__ feat,
                                               const float* __restrict__ geom,
                                               const float* __restrict__ W,
                                               const int* __restrict__ nnp,
                                               float* __restrict__ ws,
                                               float* __restrict__ out) {
    const int bid  = blockIdx.x;
    const int z    = bid >> 7;      // 0..1
    const int s    = bid & 127;     // slice / output chunk 0..127
    const int tid  = threadIdx.x;
    const int lane = tid & 63;
    const int wv   = tid >> 6;      // wave 0..3

    __shared__ float gsh[NN * 3];
    __shared__ float wred[4][7][32];   // per-wave partials
    __shared__ float sacc[7][32];      // slice ft/Gs/Gd
    __shared__ float stab[224];        // QA[96] QB[96] gam[32]

    if (tid < NN * 3) gsh[tid] = geom[z * NN * 3 + tid];
    __syncthreads();

    // ---- Phase 1: slice reduction (32 pairs x 32 channels, one float4/thread)
    const int rg = tid >> 3;           // pair within slice 0..31
    const int cg = tid & 7;            // channel group (j0 = cg*4)
    const int p  = s * 32 + rg;        // global pair index 0..4095
    const int c  = p >> 6, d = p & 63;

    float f[4];
    ld4(feat + ((size_t)z * 4096 + p) * NCI + cg * 4, f);

    float v[7][4];
    #pragma unroll
    for (int k = 0; k < 4; ++k) v[0][k] = f[k];
    #pragma unroll
    for (int x = 0; x < 3; ++x) {
        const float gc = gsh[c * 3 + x], gd = gsh[d * 3 + x];
        #pragma unroll
        for (int k = 0; k < 4; ++k) { v[1 + x][k] = gc * f[k]; v[4 + x][k] = gd * f[k]; }
    }
    // xor-reduce over the 8 rg values held by each wave (rg bits = lane[5:3])
    #pragma unroll
    for (int q = 0; q < 7; ++q)
        #pragma unroll
        for (int k = 0; k < 4; ++k) {
            float t = v[q][k];
            t += __shfl_xor(t, 8);
            t += __shfl_xor(t, 16);
            t += __shfl_xor(t, 32);
            v[q][k] = t;
        }
    if (lane < 8) {
        #pragma unroll
        for (int q = 0; q < 7; ++q)
            #pragma unroll
            for (int k = 0; k < 4; ++k) wred[wv][q][lane * 4 + k] = v[q][k];
    }
    __syncthreads();
    if (tid < 224) {
        const int q = tid >> 5, j = tid & 31;
        sacc[q][j] = wred[0][q][j] + wred[1][q][j] + wred[2][q][j] + wred[3][q][j];
    }
    __syncthreads();

    // n_norm: Python scalar -> 1-elem array; hedge int32 vs float32 bits.
    const int vn = *nnp;
    const float nnv = (vn > 0 && vn < (1 << 23)) ? (float)vn : __int_as_float(vn);
    const float scale = 1.0f / sqrtf(6.0f * nnv * nnv);

    // ---- Fold W against this block's partial (linear => atomic-accumulate)
    if (tid < 96) {
        const int x = tid >> 5, i = tid & 31;
        const float* Wp = W + x * 6 * NCO * NCI + i * NCI;   // rows m*1024 apart
        float q1 = 0.f, q23 = 0.f, q45 = 0.f, gp = 0.f;
        #pragma unroll 2
        for (int j4 = 0; j4 < 8; ++j4) {
            float w[6][4];
            #pragma unroll
            for (int m = 0; m < 6; ++m) ld4(Wp + m * 1024 + j4 * 4, w[m]);
            #pragma unroll
            for (int k = 0; k < 4; ++k) {
                const int j = j4 * 4 + k;
                const float ftj = sacc[0][j];
                const float gsj = sacc[1 + x][j];
                const float gdj = sacc[4 + x][j];
                q1  = fmaf(w[0][k], ftj, q1);
                q23 = fmaf(w[1][k] + w[2][k], ftj, q23);
                q45 = fmaf(w[3][k] + w[4][k], ftj, q45);
                gp  = fmaf(w[1][k] + w[3][k] - w[5][k], gsj, gp);
                gp  = fmaf(w[2][k] + w[4][k] + w[5][k], gdj, gp);
            }
        }
        unsafeAtomicAdd(ws + WS_QA + z * 96 + tid, scale * (q1 + q23));
        unsafeAtomicAdd(ws + WS_QB + z * 96 + tid, scale * (q1 - q45));
        unsafeAtomicAdd(ws + WS_GAM + z * 32 + i, scale * gp);
    }
    __threadfence();       // per-thread: atomics performed before barrier arrive
    __syncthreads();

    // ---- Grid barrier (all 256 blocks resident by construction)
    unsigned* ctr = (unsigned*)(ws + WS_CTR);
    if (tid == 0) {
        __hip_atomic_fetch_add(ctr, 1u, __ATOMIC_RELEASE, __HIP_MEMORY_SCOPE_AGENT);
        while (__hip_atomic_load(ctr, __ATOMIC_RELAXED, __HIP_MEMORY_SCOPE_AGENT) < NBLOCKS)
            __builtin_amdgcn_s_sleep(2);
        (void)__hip_atomic_load(ctr, __ATOMIC_ACQUIRE, __HIP_MEMORY_SCOPE_AGENT);
    }
    __syncthreads();

    // ---- Phase 2: pull finished tables (agent-scope loads, no stale L2)
    if (tid < 96)
        stab[tid] = __hip_atomic_load(ws + WS_QA + z * 96 + tid,
                                      __ATOMIC_RELAXED, __HIP_MEMORY_SCOPE_AGENT);
    else if (tid < 192)
        stab[tid] = __hip_atomic_load(ws + WS_QB + z * 96 + (tid - 96),
                                      __ATOMIC_RELAXED, __HIP_MEMORY_SCOPE_AGENT);
    else if (tid < 224)
        stab[tid] = __hip_atomic_load(ws + WS_GAM + z * 32 + (tid - 192),
                                      __ATOMIC_RELAXED, __HIP_MEMORY_SCOPE_AGENT);
    __syncthreads();

    // ---- Output: 32 (a,b) rows x 32 channels, one float4 store per thread
    const int pr = tid >> 3, i0 = (tid & 7) * 4;
    const int ab = s * 32 + pr, a = ab >> 6, b = ab & 63;
    float r[4];
    #pragma unroll
    for (int k = 0; k < 4; ++k) r[k] = stab[192 + i0 + k];
    #pragma unroll
    for (int x = 0; x < 3; ++x) {
        const float gb = gsh[b * 3 + x], ga = gsh[a * 3 + x];
        #pragma unroll
        for (int k = 0; k < 4; ++k)
            r[k] = fmaf(gb, stab[96 + x * 32 + i0 + k],
                        fmaf(-ga, stab[x * 32 + i0 + k], r[k]));
    }
    float4 o; o.x = r[0]; o.y = r[1]; o.z = r[2]; o.w = r[3];
    *(float4*)(out + ((size_t)(z * 4096 + ab)) * 32 + i0) = o;
}

extern "C" void kernel_launch(void* const* d_in, const int* in_sizes, int n_in,
                              void* d_out, int out_size, void* d_ws, size_t ws_size,
                              hipStream_t stream) {
    const float* feat = (const float*)d_in[0];   // [2,64,64,32]
    const float* geom = (const float*)d_in[1];   // [2,64,3]
    const float* W    = (const float*)d_in[2];   // [3,6144]
    const int*   nnp  = (const int*)d_in[3];     // scalar n_norm

    // Zero the table accumulators + barrier counter (2 KB). Async memset is
    // graph-capture-legal; required every call since the kernel accumulates.
    hipMemsetAsync(d_ws, 0, 2048, stream);

    k_fused<<<NBLOCKS, 256, 0, stream>>>(feat, geom, W, nnp,
                                         (float*)d_ws, (float*)d_out);
}

// Round 4
// 16.806 us; speedup vs baseline: 3.3525x; 3.3525x over previous
//
#include <hip/hip_runtime.h>
#include <math.h>

// Problem constants (fixed by the reference): B=2, N=64, CI=CO=32
#define NZ 2
#define NN 64
#define NCI 32
#define NCO 32
#define NBZ 32                    // blocks per z
#define NROWS (4096 / NBZ)        // 128 output (a,b) rows per block

__device__ __forceinline__ void ld4(const float* __restrict__ p, float* d) {
    const float4 v = *(const float4*)p;
    d[0] = v.x; d[1] = v.y; d[2] = v.z; d[3] = v.w;
}

// Single kernel, no inter-block communication. Math (linear in rel = r_b-r_a):
//   ft[j]   = sum_{c,d} f[c,d,j]
//   Gs[x,j] = sum_c g_c[x] * (sum_d f[c,d,j])     (row sums, 2-stage)
//   Gd[x,j] = sum_{c,d} g_d[x] * f[c,d,j]
//   Qm[x,i] = sum_j Wm[x,i,j] * ft[j]
//   QA = scale*(Q1+Q2+Q3)  (coeff of -g_a[x]);  QB = scale*(Q1-Q4-Q5)  (+g_b[x])
//   gam[i]  = scale * sum_{x,j} [(W2+W4-W6)*Gs + (W3+W5+W6)*Gd]
//   out[z,a,b,i] = gam[i] + sum_x (g_b[x]*QB[x,i] - g_a[x]*QA[x,i])
// Every block redundantly computes the 224-float table for its z (features
// are L2-resident after the cold fetch), then writes its 128-row chunk.
__global__ __launch_bounds__(256) void k_single(const float* __restrict__ feat,
                                                const float* __restrict__ geom,
                                                const float* __restrict__ W,
                                                const int* __restrict__ nnp,
                                                float* __restrict__ out) {
    const int bid = blockIdx.x;
    const int z   = bid >> 5;       // 0..1
    const int s   = bid & 31;       // output chunk 0..31
    const int tid = threadIdx.x;
    const int wv  = tid >> 6;       // wave 0..3
    const int lane = tid & 63;
    const int rg  = tid >> 3;       // row group 0..31
    const int cg  = tid & 7;        // channel group (j0 = cg*4)

    __shared__ float gsh[NN * 3];
    __shared__ float wred[4][7][32];   // per-wave partials
    __shared__ float sacc[7][32];      // ft, Gs[0..2], Gd[0..2]
    __shared__ float gred[3][32];
    __shared__ float stab[224];        // QA[96] QB[96] gam[32]

    if (tid < NN * 3) gsh[tid] = geom[z * NN * 3 + tid];
    __syncthreads();

    // ---- Phase 1: full per-z reduction. Thread owns rows c=2*rg+rr,
    //      channels cg*4..cg*4+3 (each float read exactly once per block).
    float ft[4] = {0.f, 0.f, 0.f, 0.f};
    float Gs[3][4] = {{0.f}};
    float Gd[3][4] = {{0.f}};
    const float* fz = feat + (size_t)z * 4096 * NCI;
    #pragma unroll
    for (int rr = 0; rr < 2; ++rr) {
        const int c = rg * 2 + rr;
        const float gc0 = gsh[c * 3 + 0], gc1 = gsh[c * 3 + 1], gc2 = gsh[c * 3 + 2];
        const float* rowp = fz + (size_t)c * 64 * NCI + cg * 4;
        float rs[4] = {0.f, 0.f, 0.f, 0.f};
        #pragma unroll 4
        for (int d = 0; d < 64; ++d) {
            float f[4];
            ld4(rowp + d * NCI, f);
            const float gd0 = gsh[d * 3 + 0], gd1 = gsh[d * 3 + 1], gd2 = gsh[d * 3 + 2];
            #pragma unroll
            for (int k = 0; k < 4; ++k) {
                rs[k] += f[k];
                Gd[0][k] = fmaf(gd0, f[k], Gd[0][k]);
                Gd[1][k] = fmaf(gd1, f[k], Gd[1][k]);
                Gd[2][k] = fmaf(gd2, f[k], Gd[2][k]);
            }
        }
        #pragma unroll
        for (int k = 0; k < 4; ++k) {
            ft[k] += rs[k];
            Gs[0][k] = fmaf(gc0, rs[k], Gs[0][k]);
            Gs[1][k] = fmaf(gc1, rs[k], Gs[1][k]);
            Gs[2][k] = fmaf(gc2, rs[k], Gs[2][k]);
        }
    }

    // Wave-level reduce over the 8 rg values per wave (lane bits 3..5).
    float v[7][4];
    #pragma unroll
    for (int k = 0; k < 4; ++k) {
        v[0][k] = ft[k];
        #pragma unroll
        for (int x = 0; x < 3; ++x) { v[1 + x][k] = Gs[x][k]; v[4 + x][k] = Gd[x][k]; }
    }
    #pragma unroll
    for (int q = 0; q < 7; ++q)
        #pragma unroll
        for (int k = 0; k < 4; ++k) {
            float t = v[q][k];
            t += __shfl_xor(t, 8);
            t += __shfl_xor(t, 16);
            t += __shfl_xor(t, 32);
            v[q][k] = t;
        }
    if (lane < 8) {
        #pragma unroll
        for (int q = 0; q < 7; ++q)
            #pragma unroll
            for (int k = 0; k < 4; ++k) wred[wv][q][lane * 4 + k] = v[q][k];
    }
    __syncthreads();
    if (tid < 224) {
        const int q = tid >> 5, j = tid & 31;
        sacc[q][j] = wred[0][q][j] + wred[1][q][j] + wred[2][q][j] + wred[3][q][j];
    }
    __syncthreads();

    // n_norm: Python scalar -> 1-elem array; hedge int32 vs float32 bits.
    const int vn = *nnp;
    const float nnv = (vn > 0 && vn < (1 << 23)) ? (float)vn : __int_as_float(vn);
    const float scale = 1.0f / sqrtf(6.0f * nnv * nnv);

    // ---- Phase 2: fold W into QA/QB/gamma (96 active threads, W L2-hot).
    if (tid < 96) {
        const int x = tid >> 5, i = tid & 31;
        const float* Wp = W + x * 6 * NCO * NCI + i * NCI;   // rows m*1024 apart
        float q1 = 0.f, q23 = 0.f, q45 = 0.f, gp = 0.f;
        #pragma unroll 2
        for (int j4 = 0; j4 < 8; ++j4) {
            float w[6][4];
            #pragma unroll
            for (int m = 0; m < 6; ++m) ld4(Wp + m * 1024 + j4 * 4, w[m]);
            #pragma unroll
            for (int k = 0; k < 4; ++k) {
                const int j = j4 * 4 + k;
                const float ftj = sacc[0][j];
                const float gsj = sacc[1 + x][j];
                const float gdj = sacc[4 + x][j];
                q1  = fmaf(w[0][k], ftj, q1);
                q23 = fmaf(w[1][k] + w[2][k], ftj, q23);
                q45 = fmaf(w[3][k] + w[4][k], ftj, q45);
                gp  = fmaf(w[1][k] + w[3][k] - w[5][k], gsj, gp);
                gp  = fmaf(w[2][k] + w[4][k] + w[5][k], gdj, gp);
            }
        }
        stab[tid]      = scale * (q1 + q23);   // QA
        stab[96 + tid] = scale * (q1 - q45);   // QB
        gred[x][i] = gp;
    }
    __syncthreads();
    if (tid < 32) stab[192 + tid] = scale * (gred[0][tid] + gred[1][tid] + gred[2][tid]);
    __syncthreads();

    // ---- Phase 3: write this block's 128 (a,b) rows, float4 stores.
    const int i0 = cg * 4;
    float qa[3][4], qb[3][4], gm[4];
    #pragma unroll
    for (int k = 0; k < 4; ++k) gm[k] = stab[192 + i0 + k];
    #pragma unroll
    for (int x = 0; x < 3; ++x)
        #pragma unroll
        for (int k = 0; k < 4; ++k) {
            qa[x][k] = stab[x * 32 + i0 + k];
            qb[x][k] = stab[96 + x * 32 + i0 + k];
        }

    #pragma unroll
    for (int u = 0; u < 4; ++u) {
        const int pr = rg + u * 32;
        const int ab = s * NROWS + pr;          // 0..4095
        const int a = ab >> 6, b = ab & 63;
        float r[4];
        #pragma unroll
        for (int k = 0; k < 4; ++k) r[k] = gm[k];
        #pragma unroll
        for (int x = 0; x < 3; ++x) {
            const float gb = gsh[b * 3 + x], ga = gsh[a * 3 + x];
            #pragma unroll
            for (int k = 0; k < 4; ++k)
                r[k] = fmaf(gb, qb[x][k], fmaf(-ga, qa[x][k], r[k]));
        }
        float4 o; o.x = r[0]; o.y = r[1]; o.z = r[2]; o.w = r[3];
        *(float4*)(out + ((size_t)(z * 4096 + ab)) * 32 + i0) = o;
    }
}

extern "C" void kernel_launch(void* const* d_in, const int* in_sizes, int n_in,
                              void* d_out, int out_size, void* d_ws, size_t ws_size,
                              hipStream_t stream) {
    const float* feat = (const float*)d_in[0];   // [2,64,64,32]
    const float* geom = (const float*)d_in[1];   // [2,64,3]
    const float* W    = (const float*)d_in[2];   // [3,6144]
    const int*   nnp  = (const int*)d_in[3];     // scalar n_norm

    k_single<<<NZ * NBZ, 256, 0, stream>>>(feat, geom, W, nnp, (float*)d_out);
}

// Round 5
// 14.331 us; speedup vs baseline: 3.9316x; 1.1727x over previous
//
#include <hip/hip_runtime.h>
#include <math.h>

// Problem constants (fixed by the reference): B=2, N=64, CI=CO=32
#define NZ 2
#define NN 64
#define NCI 32
#define NCO 32
#define NBZ 32                 // blocks per z; each block -> 128 (a,b) rows

__device__ __forceinline__ void ld4(const float* __restrict__ p, float* d) {
    const float4 v = *(const float4*)p;
    d[0] = v.x; d[1] = v.y; d[2] = v.z; d[3] = v.w;
}

// Single kernel, no inter-block communication. Math (linear in rel = r_b-r_a):
//   ft[j]   = sum_{c,d} f[c,d,j]
//   Gs[x,j] = sum_c g_c[x] * rowsum_c[j]
//   Gd[x,j] = sum_{c,d} g_d[x] * f[c,d,j]
//   Qm[x,i] = sum_j Wm[x,i,j] * ft[j]
//   QA = scale*(Q1+Q2+Q3) (coeff of -g_a[x]);  QB = scale*(Q1-Q4-Q5) (+g_b[x])
//   gam[i]  = scale * sum_{x,j} [(W2+W4-W6)*Gs + (W3+W5+W6)*Gd]
//   out[z,a,b,i] = gam[i] + sum_x (g_b[x]*QB[x,i] - g_a[x]*QA[x,i])
// Every block redundantly computes the 224-float table for its z (features
// L2-resident after cold fetch), then writes its 128-row output chunk.
// 1024 threads = 16 waves/CU for latency hiding on the 512 KB/block stream.
__global__ __launch_bounds__(1024) void k_single(const float* __restrict__ feat,
                                                 const float* __restrict__ geom,
                                                 const float* __restrict__ W,
                                                 const int* __restrict__ nnp,
                                                 float* __restrict__ out) {
    const int bid  = blockIdx.x;
    const int z    = bid >> 5;       // 0..1
    const int s    = bid & 31;       // output chunk 0..31
    const int tid  = threadIdx.x;
    const int lane = tid & 63;
    const int wv   = tid >> 6;       // wave 0..15

    __shared__ float gsh[NN * 3];        // 192
    __shared__ float wred[16][7][32];    // 3584
    __shared__ float sacc[7][32];        // 224: ft, Gs[0..2], Gd[0..2]
    __shared__ float gred[3][32];        // 96
    __shared__ float stab[224];          // QA[96] QB[96] gam[32]

    if (tid < NN * 3) gsh[tid] = geom[z * NN * 3 + tid];
    __syncthreads();

    // ---- Phase 1: full per-z reduction. Thread = (c, dh, cg):
    //      c = tid>>4 (0..63), dh = (tid>>3)&1 (d half), cg = tid&7 (j0=cg*4).
    //      32 float4 loads per thread, each feature read once per block.
    const int cg = tid & 7;
    const int dh = (tid >> 3) & 1;
    const int c  = tid >> 4;
    const float gc0 = gsh[c * 3 + 0], gc1 = gsh[c * 3 + 1], gc2 = gsh[c * 3 + 2];

    float rs[4] = {0.f, 0.f, 0.f, 0.f};
    float Gd[3][4] = {{0.f}};
    const float* rowp = feat + ((size_t)z * 4096 + c * 64 + dh * 32) * NCI + cg * 4;
    #pragma unroll 8
    for (int t = 0; t < 32; ++t) {
        float f[4];
        ld4(rowp + t * NCI, f);
        const int d = dh * 32 + t;
        const float gd0 = gsh[d * 3 + 0], gd1 = gsh[d * 3 + 1], gd2 = gsh[d * 3 + 2];
        #pragma unroll
        for (int k = 0; k < 4; ++k) {
            rs[k] += f[k];
            Gd[0][k] = fmaf(gd0, f[k], Gd[0][k]);
            Gd[1][k] = fmaf(gd1, f[k], Gd[1][k]);
            Gd[2][k] = fmaf(gd2, f[k], Gd[2][k]);
        }
    }

    // Per-lane 7x4 contribution; reduce over lane bits 3..5 (dh + c low bits).
    float v[7][4];
    #pragma unroll
    for (int k = 0; k < 4; ++k) {
        v[0][k] = rs[k];
        v[1][k] = gc0 * rs[k]; v[2][k] = gc1 * rs[k]; v[3][k] = gc2 * rs[k];
        v[4][k] = Gd[0][k];    v[5][k] = Gd[1][k];    v[6][k] = Gd[2][k];
    }
    #pragma unroll
    for (int q = 0; q < 7; ++q)
        #pragma unroll
        for (int k = 0; k < 4; ++k) {
            float t = v[q][k];
            t += __shfl_xor(t, 8);
            t += __shfl_xor(t, 16);
            t += __shfl_xor(t, 32);
            v[q][k] = t;
        }
    if (lane < 8) {
        #pragma unroll
        for (int q = 0; q < 7; ++q)
            #pragma unroll
            for (int k = 0; k < 4; ++k) wred[wv][q][lane * 4 + k] = v[q][k];
    }
    __syncthreads();
    if (tid < 224) {
        const int q = tid >> 5, j = tid & 31;
        float sum = 0.f;
        #pragma unroll
        for (int g = 0; g < 16; ++g) sum += wred[g][q][j];
        sacc[q][j] = sum;
    }
    __syncthreads();

    // n_norm: Python scalar -> 1-elem array; hedge int32 vs float32 bits.
    const int vn = *nnp;
    const float nnv = (vn > 0 && vn < (1 << 23)) ? (float)vn : __int_as_float(vn);
    const float scale = 1.0f / sqrtf(6.0f * nnv * nnv);

    // ---- Phase 2: fold W, parallel over 768 threads = (x, i, jg).
    //      Each thread: 6 ld4 of W + 4-j partial, then shfl-reduce over jg.
    if (tid < 768) {
        const int x = tid >> 8, i = (tid >> 3) & 31, jg = tid & 7;
        const float* Wp = W + x * 6 * NCO * NCI + i * NCI + jg * 4;  // m stride 1024
        float w[6][4];
        #pragma unroll
        for (int m = 0; m < 6; ++m) ld4(Wp + m * 1024, w[m]);
        float q1 = 0.f, q23 = 0.f, q45 = 0.f, gp = 0.f;
        #pragma unroll
        for (int k = 0; k < 4; ++k) {
            const int j = jg * 4 + k;
            const float ftj = sacc[0][j];
            const float gsj = sacc[1 + x][j];
            const float gdj = sacc[4 + x][j];
            q1  = fmaf(w[0][k], ftj, q1);
            q23 = fmaf(w[1][k] + w[2][k], ftj, q23);
            q45 = fmaf(w[3][k] + w[4][k], ftj, q45);
            gp  = fmaf(w[1][k] + w[3][k] - w[5][k], gsj, gp);
            gp  = fmaf(w[2][k] + w[4][k] + w[5][k], gdj, gp);
        }
        // jg lives in lane bits 0..2 -> butterfly over 1,2,4
        #pragma unroll
        for (int m = 1; m <= 4; m <<= 1) {
            q1  += __shfl_xor(q1, m);
            q23 += __shfl_xor(q23, m);
            q45 += __shfl_xor(q45, m);
            gp  += __shfl_xor(gp, m);
        }
        if (jg == 0) {
            stab[x * 32 + i]      = scale * (q1 + q23);   // QA
            stab[96 + x * 32 + i] = scale * (q1 - q45);   // QB
            gred[x][i] = gp;
        }
    }
    __syncthreads();
    if (tid < 32) stab[192 + tid] = scale * (gred[0][tid] + gred[1][tid] + gred[2][tid]);
    __syncthreads();

    // ---- Phase 3: 128 rows x 8 channel-groups -> one float4 store/thread.
    const int r  = tid >> 3;            // 0..127
    const int ab = s * 128 + r;         // 0..4095
    const int a = ab >> 6, b = ab & 63;
    const int i0 = cg * 4;
    float o4[4];
    #pragma unroll
    for (int k = 0; k < 4; ++k) o4[k] = stab[192 + i0 + k];
    #pragma unroll
    for (int x = 0; x < 3; ++x) {
        const float gb = gsh[b * 3 + x], ga = gsh[a * 3 + x];
        #pragma unroll
        for (int k = 0; k < 4; ++k)
            o4[k] = fmaf(gb, stab[96 + x * 32 + i0 + k],
                         fmaf(-ga, stab[x * 32 + i0 + k], o4[k]));
    }
    float4 o; o.x = o4[0]; o.y = o4[1]; o.z = o4[2]; o.w = o4[3];
    *(float4*)(out + ((size_t)(z * 4096 + ab)) * NCI + i0) = o;
}

extern "C" void kernel_launch(void* const* d_in, const int* in_sizes, int n_in,
                              void* d_out, int out_size, void* d_ws, size_t ws_size,
                              hipStream_t stream) {
    const float* feat = (const float*)d_in[0];   // [2,64,64,32]
    const float* geom = (const float*)d_in[1];   // [2,64,3]
    const float* W    = (const float*)d_in[2];   // [3,6144]
    const int*   nnp  = (const int*)d_in[3];     // scalar n_norm

    k_single<<<NZ * NBZ, 1024, 0, stream>>>(feat, geom, W, nnp, (float*)d_out);
}